// Round 1
// baseline (607.010 us; speedup 1.0000x reference)
//
#include <hip/hip_runtime.h>

// Shapes (fixed): B=4, L=4096, DIM=1024, INNER=512, DSTATE=8, DTRANK=64, KSZ=3
// BL = 16384 rows. Chunked scan: 64 chunks x 64 steps.

using bf16x8 = __attribute__((ext_vector_type(8))) short;
using f32x4  = __attribute__((ext_vector_type(4))) float;

__device__ __forceinline__ unsigned short f2bf(float f) {
  unsigned int u = __float_as_uint(f);
  u = u + 0x7fffu + ((u >> 16) & 1u);   // round-to-nearest-even
  return (unsigned short)(u >> 16);
}

__device__ __forceinline__ float softplusf(float x) {
  return (x > 20.f) ? x : log1pf(expf(x));
}

// ---------------- fp32 -> bf16 conversion (4 elems/thread) ----------------
__global__ __launch_bounds__(256) void cvt_bf16_kernel(
    const float* __restrict__ in, unsigned short* __restrict__ out, int n4) {
  int i = blockIdx.x * 256 + threadIdx.x;
  if (i < n4) {
    float4 v = ((const float4*)in)[i];
    ushort4 o;
    o.x = f2bf(v.x); o.y = f2bf(v.y); o.z = f2bf(v.z); o.w = f2bf(v.w);
    ((ushort4*)out)[i] = o;
  }
}

// ---------------- bf16 GEMM: C[m,n] = sum_k A[m,k]*B[n,k] ----------------
// A: MxK row-major bf16, B: NxK row-major bf16 (i.e. B^T layout), C fp32.
// m97-style: 128x128 tile, BK=32, 4 waves, 4x4 mfma_f32_16x16x32_bf16 each,
// global_load_lds width=16 staging.
__global__ __launch_bounds__(256) void gemm_bt_bf16(
    const unsigned short* __restrict__ A,
    const unsigned short* __restrict__ B,
    float* __restrict__ C, int M, int N, int K) {
  __shared__ short As[128 * 32];
  __shared__ short Bs[128 * 32];
  const int m0 = blockIdx.x * 128;
  const int n0 = blockIdx.y * 128;
  const int lane = threadIdx.x & 63;
  const int wv = threadIdx.x >> 6;
  const int wm = (wv >> 1) * 64;
  const int wn = (wv & 1) * 64;
  f32x4 acc[4][4] = {};
  const int row_a = wv * 32 + (lane >> 2);   // staging row within 128
  const int koff = (lane & 3) * 8;           // staging k-offset (elements)
  const unsigned short* gA = A + (size_t)(m0 + row_a) * K + koff;
  const unsigned short* gB = B + (size_t)(n0 + row_a) * K + koff;
  short* lA = &As[(wv * 32) * 32];           // wave-uniform LDS base
  short* lB = &Bs[(wv * 32) * 32];
  const int r = lane & 15;
  const int q = lane >> 4;
  for (int k0 = 0; k0 < K; k0 += 32) {
    __syncthreads();
    __builtin_amdgcn_global_load_lds((const __attribute__((address_space(1))) void*)(const void*)gA,
                                     (__attribute__((address_space(3))) void*)(void*)lA, 16, 0, 0);
    __builtin_amdgcn_global_load_lds((const __attribute__((address_space(1))) void*)(const void*)(gA + 16 * K),
                                     (__attribute__((address_space(3))) void*)(void*)(lA + 16 * 32), 16, 0, 0);
    __builtin_amdgcn_global_load_lds((const __attribute__((address_space(1))) void*)(const void*)gB,
                                     (__attribute__((address_space(3))) void*)(void*)lB, 16, 0, 0);
    __builtin_amdgcn_global_load_lds((const __attribute__((address_space(1))) void*)(const void*)(gB + 16 * K),
                                     (__attribute__((address_space(3))) void*)(void*)(lB + 16 * 32), 16, 0, 0);
    gA += 32; gB += 32;
    __syncthreads();   // compiler emits s_waitcnt vmcnt(0) before barrier
    bf16x8 av[4], bv[4];
#pragma unroll
    for (int i = 0; i < 4; ++i)
      av[i] = *(const bf16x8*)&As[(wm + i * 16 + r) * 32 + q * 8];
#pragma unroll
    for (int j = 0; j < 4; ++j)
      bv[j] = *(const bf16x8*)&Bs[(wn + j * 16 + r) * 32 + q * 8];
#pragma unroll
    for (int i = 0; i < 4; ++i)
#pragma unroll
      for (int j = 0; j < 4; ++j)
        acc[i][j] = __builtin_amdgcn_mfma_f32_16x16x32_bf16(av[i], bv[j], acc[i][j], 0, 0, 0);
  }
  // C/D layout: col = lane&15, row = (lane>>4)*4 + reg
#pragma unroll
  for (int i = 0; i < 4; ++i)
#pragma unroll
    for (int j = 0; j < 4; ++j)
#pragma unroll
      for (int t = 0; t < 4; ++t)
        C[(size_t)(m0 + wm + i * 16 + q * 4 + t) * N + (n0 + wn + j * 16 + r)] = acc[i][j][t];
}

// ---------------- depthwise conv (k=3, pad=1) + SiLU ----------------
// xb half -> fp32 buffer; zb half -> bf16 into cat[..., 512:1024]
__global__ __launch_bounds__(256) void conv_silu_kernel(
    const float* __restrict__ h, const float* __restrict__ Kx, const float* __restrict__ Kz,
    float* __restrict__ xb, unsigned short* __restrict__ cat) {
  int tid = blockIdx.x * 256 + threadIdx.x;  // over 16384*1024
  int ch = tid & 1023;
  int bl = tid >> 10;
  int l = bl & 4095;
  float k0, k1, k2;
  int c;
  if (ch < 512) { c = ch;       k0 = Kx[c * 3]; k1 = Kx[c * 3 + 1]; k2 = Kx[c * 3 + 2]; }
  else          { c = ch - 512; k0 = Kz[c * 3]; k1 = Kz[c * 3 + 1]; k2 = Kz[c * 3 + 2]; }
  size_t idx = (size_t)bl * 1024 + ch;
  float um = (l > 0)    ? h[idx - 1024] : 0.f;
  float u0 = h[idx];
  float up = (l < 4095) ? h[idx + 1024] : 0.f;
  float v = um * k0 + u0 * k1 + up * k2;
  float o = v / (1.f + expf(-v));  // silu
  if (ch < 512) xb[(size_t)bl * 512 + c] = o;
  else          cat[idx] = f2bf(o);
}

// ---------------- xproj + delta + tanh(b/c) fused ----------------
// 1 wave per block, 8 rows per block (2048 blocks).
__global__ __launch_bounds__(64) void proj_delta_kernel(
    const float* __restrict__ xb, const float* __restrict__ Wx,
    const float* __restrict__ Wd, const float* __restrict__ bdt,
    float* __restrict__ delta, float* __restrict__ bterm, float* __restrict__ cterm) {
  __shared__ float rows[8][512];
  __shared__ float dtr[8][64];
  const int lane = threadIdx.x;
  const size_t r0 = (size_t)blockIdx.x * 8;
  const float4* src = (const float4*)(xb + r0 * 512);
  float4* dst = (float4*)&rows[0][0];
#pragma unroll
  for (int i = 0; i < 16; ++i) dst[lane + 64 * i] = src[lane + 64 * i];
  __syncthreads();
  {  // dt_raw: outputs o = lane (0..63)
    float acc[8] = {0, 0, 0, 0, 0, 0, 0, 0};
    const float* w = Wx + lane * 512;
    for (int cc = 0; cc < 512; cc += 4) {
      float4 w4 = *(const float4*)(w + cc);
#pragma unroll
      for (int rr = 0; rr < 8; ++rr) {
        float4 x4 = *(const float4*)&rows[rr][cc];
        acc[rr] += w4.x * x4.x + w4.y * x4.y + w4.z * x4.z + w4.w * x4.w;
      }
    }
#pragma unroll
    for (int rr = 0; rr < 8; ++rr) dtr[rr][lane] = acc[rr];
  }
  if (lane < 16) {  // b_raw (o=64..71), c_raw (o=72..79)
    float acc[8] = {0, 0, 0, 0, 0, 0, 0, 0};
    const float* w = Wx + (64 + lane) * 512;
    for (int cc = 0; cc < 512; cc += 4) {
      float4 w4 = *(const float4*)(w + cc);
#pragma unroll
      for (int rr = 0; rr < 8; ++rr) {
        float4 x4 = *(const float4*)&rows[rr][cc];
        acc[rr] += w4.x * x4.x + w4.y * x4.y + w4.z * x4.z + w4.w * x4.w;
      }
    }
#pragma unroll
    for (int rr = 0; rr < 8; ++rr) {
      float tv = tanhf(acc[rr]);
      if (lane < 8) bterm[(r0 + rr) * 8 + lane] = tv;
      else          cterm[(r0 + rr) * 8 + (lane - 8)] = tv;
    }
  }
  __syncthreads();
  // delta = clip(softplus(dt_raw @ Wd^T + b_dt), 1e-4, 1)
  for (int j = 0; j < 8; ++j) {
    int c = lane + 64 * j;
    const float* wd = Wd + c * 64;
    float bb = bdt[c];
    float acc[8] = {bb, bb, bb, bb, bb, bb, bb, bb};
    for (int rr = 0; rr < 64; rr += 4) {
      float4 w4 = *(const float4*)(wd + rr);
#pragma unroll
      for (int r2 = 0; r2 < 8; ++r2) {
        float4 d4 = *(const float4*)&dtr[r2][rr];
        acc[r2] += w4.x * d4.x + w4.y * d4.y + w4.z * d4.z + w4.w * d4.w;
      }
    }
#pragma unroll
    for (int r2 = 0; r2 < 8; ++r2) {
      float sp = softplusf(acc[r2]);
      delta[(r0 + r2) * 512 + c] = fminf(fmaxf(sp, 1e-4f), 1.f);
    }
  }
}

// ---------------- chunked selective scan ----------------
// thread layout in p1/p3: lane = (c_local<<3) | s ; block covers 32 channels.
// grid id = ((b*16 + cg)*64 + chunk)
__global__ __launch_bounds__(256) void scan_p1(
    const float* __restrict__ delta, const float* __restrict__ bterm,
    const float* __restrict__ xb, const float* __restrict__ A_log,
    float* __restrict__ Aprod, float* __restrict__ Bpart) {
  int t = threadIdx.x;
  int s = t & 7, cl = t >> 3;
  int id = blockIdx.x;
  int chunk = id & 63, cg = (id >> 6) & 15, b = id >> 10;
  int c = cg * 32 + cl;
  float a = softplusf(A_log[c * 8 + s]) + 1e-4f;
  int l0 = chunk * 64;
  size_t base  = ((size_t)b * 4096 + l0) * 512 + c;
  size_t bbase = ((size_t)b * 4096 + l0) * 8 + s;
  float Ap = 1.f, S = 0.f;
  for (int i = 0; i < 64; ++i) {
    float dl = delta[base];
    float xv = xb[base];
    float bt = bterm[bbase];
    float dec = fminf(fmaxf(expf(-dl * a), 1e-4f), 1.f);
    S = dec * S + (1.f - dec) * (bt * xv);
    Ap *= dec;
    base += 512; bbase += 8;
  }
  size_t o = (((size_t)b * 512 + c) * 8 + s) * 64 + chunk;
  Aprod[o] = Ap; Bpart[o] = S;
}

__global__ __launch_bounds__(256) void scan_p2(
    const float* __restrict__ Aprod, const float* __restrict__ Bpart,
    float* __restrict__ initst) {
  int t = blockIdx.x * 256 + threadIdx.x;  // 16384 threads: (b,c,s)
  size_t base = (size_t)t * 64;
  float st = 0.f;
  for (int ch = 0; ch < 64; ++ch) {
    initst[base + ch] = st;
    st = Aprod[base + ch] * st + Bpart[base + ch];
  }
}

__global__ __launch_bounds__(256) void scan_p3(
    const float* __restrict__ delta, const float* __restrict__ bterm,
    const float* __restrict__ cterm, const float* __restrict__ xb,
    const float* __restrict__ A_log, const float* __restrict__ Dp,
    const float* __restrict__ initst, unsigned short* __restrict__ cat) {
  int t = threadIdx.x;
  int s = t & 7, cl = t >> 3;
  int id = blockIdx.x;
  int chunk = id & 63, cg = (id >> 6) & 15, b = id >> 10;
  int c = cg * 32 + cl;
  float a = softplusf(A_log[c * 8 + s]) + 1e-4f;
  float Dv = Dp[c];
  size_t o = (((size_t)b * 512 + c) * 8 + s) * 64 + chunk;
  float S = initst[o];
  int l0 = chunk * 64;
  size_t base  = ((size_t)b * 4096 + l0) * 512 + c;
  size_t bbase = ((size_t)b * 4096 + l0) * 8 + s;
  size_t cbase = ((size_t)b * 4096 + l0) * 1024 + c;   // y goes to cat[..., :512]
  for (int i = 0; i < 64; ++i) {
    float dl = delta[base];
    float xv = xb[base];
    float bt = bterm[bbase];
    float ct = cterm[bbase];
    float dec = fminf(fmaxf(expf(-dl * a), 1e-4f), 1.f);
    S = dec * S + (1.f - dec) * (bt * xv);
    float part = S * ct;
    part += __shfl_xor(part, 1);
    part += __shfl_xor(part, 2);
    part += __shfl_xor(part, 4);
    if (s == 0) cat[cbase] = f2bf(part + Dv * xv);
    base += 512; bbase += 8; cbase += 1024;
  }
}

// ---------------- launch ----------------
extern "C" void kernel_launch(void* const* d_in, const int* in_sizes, int n_in,
                              void* d_out, int out_size, void* d_ws, size_t ws_size,
                              hipStream_t stream) {
  (void)in_sizes; (void)n_in; (void)out_size; (void)ws_size;
  const float* x       = (const float*)d_in[0];
  const float* W_in    = (const float*)d_in[1];
  const float* Kx      = (const float*)d_in[2];
  const float* Kz      = (const float*)d_in[3];
  const float* W_xproj = (const float*)d_in[4];
  const float* W_dt    = (const float*)d_in[5];
  const float* b_dt    = (const float*)d_in[6];
  const float* A_log   = (const float*)d_in[7];
  const float* Dp      = (const float*)d_in[8];
  const float* W_out   = (const float*)d_in[9];
  float* out = (float*)d_out;

  // workspace layout (118.5 MB total)
  char* w = (char*)d_ws;
  unsigned short* xbf   = (unsigned short*)(w);              // 33.5MB; reused as cat (bf16) later
  float* xb     = (float*)(w + 33554432);                    // 33.5MB
  float* delta  = (float*)(w + 67108864);                    // 33.5MB
  float* bterm  = (float*)(w + 100663296);                   // 0.5MB
  float* cterm  = (float*)(w + 101187584);                   // 0.5MB
  float* Aprod  = (float*)(w + 101711872);                   // 4MB
  float* Bpart  = (float*)(w + 105906176);                   // 4MB
  float* initst = (float*)(w + 110100480);                   // 4MB
  unsigned short* winbf  = (unsigned short*)(w + 114294784); // 2MB
  unsigned short* woutbf = (unsigned short*)(w + 116391936); // 2MB
  float* h = out;  // d_out doubles as the h scratch (fully rewritten by final GEMM)

  cvt_bf16_kernel<<<16384, 256, 0, stream>>>(x, xbf, 4194304);
  cvt_bf16_kernel<<<1024, 256, 0, stream>>>(W_in, winbf, 262144);
  cvt_bf16_kernel<<<1024, 256, 0, stream>>>(W_out, woutbf, 262144);

  gemm_bt_bf16<<<dim3(128, 8), 256, 0, stream>>>(xbf, winbf, h, 16384, 1024, 1024);

  conv_silu_kernel<<<65536, 256, 0, stream>>>(h, Kx, Kz, xb, xbf /*cat*/);

  proj_delta_kernel<<<2048, 64, 0, stream>>>(xb, W_xproj, W_dt, b_dt, delta, bterm, cterm);

  scan_p1<<<4096, 256, 0, stream>>>(delta, bterm, xb, A_log, Aprod, Bpart);
  scan_p2<<<64, 256, 0, stream>>>(Aprod, Bpart, initst);
  scan_p3<<<4096, 256, 0, stream>>>(delta, bterm, cterm, xb, A_log, Dp, initst, xbf /*cat*/);

  gemm_bt_bf16<<<dim3(128, 8), 256, 0, stream>>>(xbf, woutbf, out, 16384, 1024, 1024);
}

// Round 2
// 514.368 us; speedup vs baseline: 1.1801x; 1.1801x over previous
//
#include <hip/hip_runtime.h>

// Shapes (fixed): B=4, L=4096, DIM=1024, INNER=512, DSTATE=8, DTRANK=64, KSZ=3
// BL = 16384 rows. Chunked scan: 64 chunks x 64 steps.

using bf16x8 = __attribute__((ext_vector_type(8))) short;
using f32x4  = __attribute__((ext_vector_type(4))) float;

__device__ __forceinline__ unsigned short f2bf(float f) {
  unsigned int u = __float_as_uint(f);
  u = u + 0x7fffu + ((u >> 16) & 1u);   // round-to-nearest-even
  return (unsigned short)(u >> 16);
}

__device__ __forceinline__ float softplusf(float x) {
  return (x > 20.f) ? x : log1pf(expf(x));
}

// ---------------- fp32 -> bf16 conversion (4 elems/thread) ----------------
__global__ __launch_bounds__(256) void cvt_bf16_kernel(
    const float* __restrict__ in, unsigned short* __restrict__ out, int n4) {
  int i = blockIdx.x * 256 + threadIdx.x;
  if (i < n4) {
    float4 v = ((const float4*)in)[i];
    ushort4 o;
    o.x = f2bf(v.x); o.y = f2bf(v.y); o.z = f2bf(v.z); o.w = f2bf(v.w);
    ((ushort4*)out)[i] = o;
  }
}

// pad/convert W_xproj (80x512 f32) -> (128x512 bf16, rows 80..127 = 0)
__global__ __launch_bounds__(256) void cvt_wxp_kernel(
    const float* __restrict__ Wx, unsigned short* __restrict__ out) {
  int i = blockIdx.x * 256 + threadIdx.x;  // 128*512
  int row = i >> 9;
  out[i] = (row < 80) ? f2bf(Wx[i]) : (unsigned short)0;
}

// ---------------- bf16 GEMM: C[m,n] = sum_k A[m,k]*B[n,k] ----------------
// A: MxK row-major bf16, B: NxK row-major bf16 (B^T layout), C fp32.
// m97-style: 128x128 tile, BK=32, 4 waves, 4x4 mfma_f32_16x16x32_bf16.
__global__ __launch_bounds__(256) void gemm_bt_bf16(
    const unsigned short* __restrict__ A,
    const unsigned short* __restrict__ B,
    float* __restrict__ C, int M, int N, int K) {
  __shared__ short As[128 * 32];
  __shared__ short Bs[128 * 32];
  const int m0 = blockIdx.x * 128;
  const int n0 = blockIdx.y * 128;
  const int lane = threadIdx.x & 63;
  const int wv = threadIdx.x >> 6;
  const int wm = (wv >> 1) * 64;
  const int wn = (wv & 1) * 64;
  f32x4 acc[4][4] = {};
  const int row_a = wv * 32 + (lane >> 2);   // staging row within 128
  const int koff = (lane & 3) * 8;           // staging k-offset (elements)
  const unsigned short* gA = A + (size_t)(m0 + row_a) * K + koff;
  const unsigned short* gB = B + (size_t)(n0 + row_a) * K + koff;
  short* lA = &As[(wv * 32) * 32];           // wave-uniform LDS base
  short* lB = &Bs[(wv * 32) * 32];
  const int r = lane & 15;
  const int q = lane >> 4;
  for (int k0 = 0; k0 < K; k0 += 32) {
    __syncthreads();
    __builtin_amdgcn_global_load_lds((const __attribute__((address_space(1))) void*)(const void*)gA,
                                     (__attribute__((address_space(3))) void*)(void*)lA, 16, 0, 0);
    __builtin_amdgcn_global_load_lds((const __attribute__((address_space(1))) void*)(const void*)(gA + 16 * K),
                                     (__attribute__((address_space(3))) void*)(void*)(lA + 16 * 32), 16, 0, 0);
    __builtin_amdgcn_global_load_lds((const __attribute__((address_space(1))) void*)(const void*)gB,
                                     (__attribute__((address_space(3))) void*)(void*)lB, 16, 0, 0);
    __builtin_amdgcn_global_load_lds((const __attribute__((address_space(1))) void*)(const void*)(gB + 16 * K),
                                     (__attribute__((address_space(3))) void*)(void*)(lB + 16 * 32), 16, 0, 0);
    gA += 32; gB += 32;
    __syncthreads();
    bf16x8 av[4], bv[4];
#pragma unroll
    for (int i = 0; i < 4; ++i)
      av[i] = *(const bf16x8*)&As[(wm + i * 16 + r) * 32 + q * 8];
#pragma unroll
    for (int j = 0; j < 4; ++j)
      bv[j] = *(const bf16x8*)&Bs[(wn + j * 16 + r) * 32 + q * 8];
#pragma unroll
    for (int i = 0; i < 4; ++i)
#pragma unroll
      for (int j = 0; j < 4; ++j)
        acc[i][j] = __builtin_amdgcn_mfma_f32_16x16x32_bf16(av[i], bv[j], acc[i][j], 0, 0, 0);
  }
  // C/D layout: col = lane&15, row = (lane>>4)*4 + reg
#pragma unroll
  for (int i = 0; i < 4; ++i)
#pragma unroll
    for (int j = 0; j < 4; ++j)
#pragma unroll
      for (int t = 0; t < 4; ++t)
        C[(size_t)(m0 + wm + i * 16 + q * 4 + t) * N + (n0 + wn + j * 16 + r)] = acc[i][j][t];
}

// ---------------- depthwise conv (k=3, pad=1) + SiLU ----------------
__global__ __launch_bounds__(256) void conv_silu_kernel(
    const float* __restrict__ h, const float* __restrict__ Kx, const float* __restrict__ Kz,
    float* __restrict__ xb, unsigned short* __restrict__ xbbf,
    unsigned short* __restrict__ cat) {
  int tid = blockIdx.x * 256 + threadIdx.x;  // over 16384*1024
  int ch = tid & 1023;
  int bl = tid >> 10;
  int l = bl & 4095;
  float k0, k1, k2;
  int c;
  if (ch < 512) { c = ch;       k0 = Kx[c * 3]; k1 = Kx[c * 3 + 1]; k2 = Kx[c * 3 + 2]; }
  else          { c = ch - 512; k0 = Kz[c * 3]; k1 = Kz[c * 3 + 1]; k2 = Kz[c * 3 + 2]; }
  size_t idx = (size_t)bl * 1024 + ch;
  float um = (l > 0)    ? h[idx - 1024] : 0.f;
  float u0 = h[idx];
  float up = (l < 4095) ? h[idx + 1024] : 0.f;
  float v = um * k0 + u0 * k1 + up * k2;
  float o = v / (1.f + expf(-v));  // silu
  if (ch < 512) { xb[(size_t)bl * 512 + c] = o; xbbf[(size_t)bl * 512 + c] = f2bf(o); }
  else          cat[idx] = f2bf(o);
}

// ---------------- split proj: dtr -> bf16, b/c -> tanh ----------------
__global__ __launch_bounds__(256) void prep_dtbc_kernel(
    const float* __restrict__ proj, unsigned short* __restrict__ dtr,
    float* __restrict__ bterm, float* __restrict__ cterm) {
  int i = blockIdx.x * 256 + threadIdx.x;  // 16384*128
  int row = i >> 7, col = i & 127;
  float v = proj[i];
  if (col < 64)      dtr[row * 64 + col] = f2bf(v);
  else if (col < 72) bterm[row * 8 + (col - 64)] = tanhf(v);
  else if (col < 80) cterm[row * 8 + (col - 72)] = tanhf(v);
}

// ---------------- chunked selective scan ----------------
// One thread owns one (b, c, chunk) with all 8 DSTATE lanes in registers.
// Lanes -> consecutive c: coalesced draw/xb; bterm/cterm wave-uniform broadcast.
// delta = clip(softplus(draw + b_dt[c]), 1e-4, 1) computed inline.
__global__ __launch_bounds__(256) void scan_p1(
    const float* __restrict__ draw, const float* __restrict__ bterm,
    const float* __restrict__ xb, const float* __restrict__ A_log,
    const float* __restrict__ bdt,
    float* __restrict__ Aprod, float* __restrict__ Bpart) {
  int tid = threadIdx.x;
  int gid = blockIdx.x;
  int chunk = gid & 63, half = (gid >> 6) & 1, b = gid >> 7;
  int c = half * 256 + tid;
  float4 a0 = *(const float4*)&A_log[c * 8];
  float4 a1 = *(const float4*)&A_log[c * 8 + 4];
  float a[8] = {a0.x, a0.y, a0.z, a0.w, a1.x, a1.y, a1.z, a1.w};
#pragma unroll
  for (int s = 0; s < 8; ++s) a[s] = softplusf(a[s]) + 1e-4f;
  float bb = bdt[c];
  int l0 = chunk * 64;
  size_t base  = ((size_t)b * 4096 + l0) * 512 + c;
  size_t bbase = ((size_t)b * 4096 + l0) * 8;
  float S[8] = {}, Ap[8] = {1.f, 1.f, 1.f, 1.f, 1.f, 1.f, 1.f, 1.f};
  for (int i = 0; i < 64; ++i) {
    float dr = draw[base] + bb;
    float xv = xb[base];
    float delta = fminf(fmaxf(softplusf(dr), 1e-4f), 1.f);
    float4 bt0 = *(const float4*)&bterm[bbase];
    float4 bt1 = *(const float4*)&bterm[bbase + 4];
    float bt[8] = {bt0.x, bt0.y, bt0.z, bt0.w, bt1.x, bt1.y, bt1.z, bt1.w};
#pragma unroll
    for (int s = 0; s < 8; ++s) {
      float dec = fminf(fmaxf(expf(-delta * a[s]), 1e-4f), 1.f);
      S[s] = dec * S[s] + (1.f - dec) * (bt[s] * xv);
      Ap[s] *= dec;
    }
    base += 512; bbase += 8;
  }
  size_t o = (((size_t)b * 512 + c) * 8) * 64 + chunk;
#pragma unroll
  for (int s = 0; s < 8; ++s) { Aprod[o + s * 64] = Ap[s]; Bpart[o + s * 64] = S[s]; }
}

__global__ __launch_bounds__(256) void scan_p2(
    const float* __restrict__ Aprod, const float* __restrict__ Bpart,
    float* __restrict__ initst) {
  int t = blockIdx.x * 256 + threadIdx.x;  // 16384 threads: (b,c,s)
  size_t base = (size_t)t * 64;
  float st = 0.f;
  for (int ch = 0; ch < 64; ++ch) {
    initst[base + ch] = st;
    st = Aprod[base + ch] * st + Bpart[base + ch];
  }
}

__global__ __launch_bounds__(256) void scan_p3(
    const float* __restrict__ draw, const float* __restrict__ bterm,
    const float* __restrict__ cterm, const float* __restrict__ xb,
    const float* __restrict__ A_log, const float* __restrict__ bdt,
    const float* __restrict__ Dp,
    const float* __restrict__ initst, unsigned short* __restrict__ cat) {
  int tid = threadIdx.x;
  int gid = blockIdx.x;
  int chunk = gid & 63, half = (gid >> 6) & 1, b = gid >> 7;
  int c = half * 256 + tid;
  float4 a0 = *(const float4*)&A_log[c * 8];
  float4 a1 = *(const float4*)&A_log[c * 8 + 4];
  float a[8] = {a0.x, a0.y, a0.z, a0.w, a1.x, a1.y, a1.z, a1.w};
#pragma unroll
  for (int s = 0; s < 8; ++s) a[s] = softplusf(a[s]) + 1e-4f;
  float bb = bdt[c];
  float Dv = Dp[c];
  size_t o = (((size_t)b * 512 + c) * 8) * 64 + chunk;
  float S[8];
#pragma unroll
  for (int s = 0; s < 8; ++s) S[s] = initst[o + s * 64];
  int l0 = chunk * 64;
  size_t base  = ((size_t)b * 4096 + l0) * 512 + c;
  size_t bbase = ((size_t)b * 4096 + l0) * 8;
  size_t cbase = ((size_t)b * 4096 + l0) * 1024 + c;   // y -> cat[..., :512]
  for (int i = 0; i < 64; ++i) {
    float dr = draw[base] + bb;
    float xv = xb[base];
    float delta = fminf(fmaxf(softplusf(dr), 1e-4f), 1.f);
    float4 bt0 = *(const float4*)&bterm[bbase];
    float4 bt1 = *(const float4*)&bterm[bbase + 4];
    float4 ct0 = *(const float4*)&cterm[bbase];
    float4 ct1 = *(const float4*)&cterm[bbase + 4];
    float bt[8] = {bt0.x, bt0.y, bt0.z, bt0.w, bt1.x, bt1.y, bt1.z, bt1.w};
    float ct[8] = {ct0.x, ct0.y, ct0.z, ct0.w, ct1.x, ct1.y, ct1.z, ct1.w};
    float acc = Dv * xv;
#pragma unroll
    for (int s = 0; s < 8; ++s) {
      float dec = fminf(fmaxf(expf(-delta * a[s]), 1e-4f), 1.f);
      S[s] = dec * S[s] + (1.f - dec) * (bt[s] * xv);
      acc += S[s] * ct[s];
    }
    cat[cbase] = f2bf(acc);
    base += 512; bbase += 8; cbase += 1024;
  }
}

// ---------------- launch ----------------
extern "C" void kernel_launch(void* const* d_in, const int* in_sizes, int n_in,
                              void* d_out, int out_size, void* d_ws, size_t ws_size,
                              hipStream_t stream) {
  (void)in_sizes; (void)n_in; (void)out_size; (void)ws_size;
  const float* x       = (const float*)d_in[0];
  const float* W_in    = (const float*)d_in[1];
  const float* Kx      = (const float*)d_in[2];
  const float* Kz      = (const float*)d_in[3];
  const float* W_xproj = (const float*)d_in[4];
  const float* W_dt    = (const float*)d_in[5];
  const float* b_dt    = (const float*)d_in[6];
  const float* A_log   = (const float*)d_in[7];
  const float* Dp      = (const float*)d_in[8];
  const float* W_out   = (const float*)d_in[9];
  float* out = (float*)d_out;

  // workspace layout (~135 MB), with dead-buffer overlays
  char* w = (char*)d_ws;
  unsigned short* xbf  = (unsigned short*)(w);               // 33.5MB x bf16; reused as cat
  float* xb    = (float*)(w + 33554432);                     // 33.5MB fp32 xb (scan)
  float* draw  = (float*)(w + 67108864);                     // 33.5MB delta_raw; head doubles as proj
  float* bterm = (float*)(w + 100663296);                    // 0.5MB
  float* cterm = (float*)(w + 101187584);                    // 0.5MB
  float* Aprod = (float*)(w + 101711872);                    // 4MB; head doubles as dtr (dead before p1)
  float* Bpart = (float*)(w + 105906176);                    // 4MB; head doubles as wxp/wd (dead before p1)
  float* initst = (float*)(w + 110100480);                   // 4MB
  unsigned short* winbf  = (unsigned short*)(w + 114294784); // 2MB
  unsigned short* woutbf = (unsigned short*)(w + 116391936); // 2MB
  unsigned short* xbbf   = (unsigned short*)(w + 118489088); // 16.8MB bf16 xb
  float* proj = draw;                                        // 16384x128, dead after prep_dtbc
  unsigned short* dtr    = (unsigned short*)Aprod;           // 16384x64 bf16
  unsigned short* wxp_bf = (unsigned short*)Bpart;           // 128x512 bf16
  unsigned short* wd_bf  = (unsigned short*)Bpart + 65536;   // 512x64 bf16
  float* h = out;  // d_out doubles as h scratch (fully rewritten by final GEMM)

  cvt_bf16_kernel<<<16384, 256, 0, stream>>>(x, xbf, 4194304);
  cvt_bf16_kernel<<<1024, 256, 0, stream>>>(W_in, winbf, 262144);
  cvt_bf16_kernel<<<1024, 256, 0, stream>>>(W_out, woutbf, 262144);
  cvt_bf16_kernel<<<32, 256, 0, stream>>>(W_dt, wd_bf, 8192);
  cvt_wxp_kernel<<<256, 256, 0, stream>>>(W_xproj, wxp_bf);

  gemm_bt_bf16<<<dim3(128, 8), 256, 0, stream>>>(xbf, winbf, h, 16384, 1024, 1024);

  conv_silu_kernel<<<65536, 256, 0, stream>>>(h, Kx, Kz, xb, xbbf, xbf /*cat*/);

  gemm_bt_bf16<<<dim3(128, 1), 256, 0, stream>>>(xbbf, wxp_bf, proj, 16384, 128, 512);
  prep_dtbc_kernel<<<8192, 256, 0, stream>>>(proj, dtr, bterm, cterm);
  gemm_bt_bf16<<<dim3(128, 4), 256, 0, stream>>>(dtr, wd_bf, draw, 16384, 512, 64);

  scan_p1<<<512, 256, 0, stream>>>(draw, bterm, xb, A_log, b_dt, Aprod, Bpart);
  scan_p2<<<64, 256, 0, stream>>>(Aprod, Bpart, initst);
  scan_p3<<<512, 256, 0, stream>>>(draw, bterm, cterm, xb, A_log, b_dt, Dp, initst, xbf /*cat*/);

  gemm_bt_bf16<<<dim3(128, 8), 256, 0, stream>>>(xbf, woutbf, out, 16384, 1024, 1024);
}

// Round 3
// 371.239 us; speedup vs baseline: 1.6351x; 1.3855x over previous
//
#include <hip/hip_runtime.h>

// Shapes (fixed): B=4, L=4096, DIM=1024, INNER=512, DSTATE=8, DTRANK=64, KSZ=3
// BL = 16384 rows. Chunked scan: 128 chunks x 32 steps, chunk-major summaries.

using bf16x8 = __attribute__((ext_vector_type(8))) short;
using f32x4  = __attribute__((ext_vector_type(4))) float;

__device__ __forceinline__ unsigned short f2bf(float f) {
  unsigned int u = __float_as_uint(f);
  u = u + 0x7fffu + ((u >> 16) & 1u);   // round-to-nearest-even
  return (unsigned short)(u >> 16);
}

// fast softplus: log1p(exp(x)) via hardware exp/log; exact passthrough for x>15
__device__ __forceinline__ float fsoftplus(float x) {
  return (x > 15.f) ? x : __logf(1.f + __expf(x));
}

__device__ __forceinline__ float ftanh(float x) {
  float v = fminf(fmaxf(x, -15.f), 15.f);
  float e = __expf(2.f * v);
  return (e - 1.f) / (e + 1.f);
}

// ---------------- fp32 -> bf16 conversion (4 elems/thread) ----------------
__global__ __launch_bounds__(256) void cvt_bf16_kernel(
    const float* __restrict__ in, unsigned short* __restrict__ out, int n4) {
  int i = blockIdx.x * 256 + threadIdx.x;
  if (i < n4) {
    float4 v = ((const float4*)in)[i];
    ushort4 o;
    o.x = f2bf(v.x); o.y = f2bf(v.y); o.z = f2bf(v.z); o.w = f2bf(v.w);
    ((ushort4*)out)[i] = o;
  }
}

// pad/convert W_xproj (80x512 f32) -> (128x512 bf16, rows 80..127 = 0)
__global__ __launch_bounds__(256) void cvt_wxp_kernel(
    const float* __restrict__ Wx, unsigned short* __restrict__ out) {
  int i = blockIdx.x * 256 + threadIdx.x;  // 128*512
  int row = i >> 9;
  out[i] = (row < 80) ? f2bf(Wx[i]) : (unsigned short)0;
}

// ---------------- bf16 GEMM: C[m,n] = sum_k A[m,k]*B[n,k] ----------------
// A: MxK row-major bf16, B: NxK row-major bf16 (B^T layout), C fp32.
// m97-style: 128x128 tile, BK=32, 4 waves, 4x4 mfma_f32_16x16x32_bf16.
__global__ __launch_bounds__(256) void gemm_bt_bf16(
    const unsigned short* __restrict__ A,
    const unsigned short* __restrict__ B,
    float* __restrict__ C, int M, int N, int K) {
  __shared__ short As[128 * 32];
  __shared__ short Bs[128 * 32];
  const int m0 = blockIdx.x * 128;
  const int n0 = blockIdx.y * 128;
  const int lane = threadIdx.x & 63;
  const int wv = threadIdx.x >> 6;
  const int wm = (wv >> 1) * 64;
  const int wn = (wv & 1) * 64;
  f32x4 acc[4][4] = {};
  const int row_a = wv * 32 + (lane >> 2);   // staging row within 128
  const int koff = (lane & 3) * 8;           // staging k-offset (elements)
  const unsigned short* gA = A + (size_t)(m0 + row_a) * K + koff;
  const unsigned short* gB = B + (size_t)(n0 + row_a) * K + koff;
  short* lA = &As[(wv * 32) * 32];           // wave-uniform LDS base
  short* lB = &Bs[(wv * 32) * 32];
  const int r = lane & 15;
  const int q = lane >> 4;
  for (int k0 = 0; k0 < K; k0 += 32) {
    __syncthreads();
    __builtin_amdgcn_global_load_lds((const __attribute__((address_space(1))) void*)(const void*)gA,
                                     (__attribute__((address_space(3))) void*)(void*)lA, 16, 0, 0);
    __builtin_amdgcn_global_load_lds((const __attribute__((address_space(1))) void*)(const void*)(gA + 16 * K),
                                     (__attribute__((address_space(3))) void*)(void*)(lA + 16 * 32), 16, 0, 0);
    __builtin_amdgcn_global_load_lds((const __attribute__((address_space(1))) void*)(const void*)gB,
                                     (__attribute__((address_space(3))) void*)(void*)lB, 16, 0, 0);
    __builtin_amdgcn_global_load_lds((const __attribute__((address_space(1))) void*)(const void*)(gB + 16 * K),
                                     (__attribute__((address_space(3))) void*)(void*)(lB + 16 * 32), 16, 0, 0);
    gA += 32; gB += 32;
    __syncthreads();
    bf16x8 av[4], bv[4];
#pragma unroll
    for (int i = 0; i < 4; ++i)
      av[i] = *(const bf16x8*)&As[(wm + i * 16 + r) * 32 + q * 8];
#pragma unroll
    for (int j = 0; j < 4; ++j)
      bv[j] = *(const bf16x8*)&Bs[(wn + j * 16 + r) * 32 + q * 8];
#pragma unroll
    for (int i = 0; i < 4; ++i)
#pragma unroll
      for (int j = 0; j < 4; ++j)
        acc[i][j] = __builtin_amdgcn_mfma_f32_16x16x32_bf16(av[i], bv[j], acc[i][j], 0, 0, 0);
  }
  // C/D layout: col = lane&15, row = (lane>>4)*4 + reg
#pragma unroll
  for (int i = 0; i < 4; ++i)
#pragma unroll
    for (int j = 0; j < 4; ++j)
#pragma unroll
      for (int t = 0; t < 4; ++t)
        C[(size_t)(m0 + wm + i * 16 + q * 4 + t) * N + (n0 + wn + j * 16 + r)] = acc[i][j][t];
}

// ---------------- depthwise conv (k=3, pad=1) + SiLU ----------------
__global__ __launch_bounds__(256) void conv_silu_kernel(
    const float* __restrict__ h, const float* __restrict__ Kx, const float* __restrict__ Kz,
    float* __restrict__ xb, unsigned short* __restrict__ xbbf,
    unsigned short* __restrict__ cat) {
  int tid = blockIdx.x * 256 + threadIdx.x;  // over 16384*1024
  int ch = tid & 1023;
  int bl = tid >> 10;
  int l = bl & 4095;
  float k0, k1, k2;
  int c;
  if (ch < 512) { c = ch;       k0 = Kx[c * 3]; k1 = Kx[c * 3 + 1]; k2 = Kx[c * 3 + 2]; }
  else          { c = ch - 512; k0 = Kz[c * 3]; k1 = Kz[c * 3 + 1]; k2 = Kz[c * 3 + 2]; }
  size_t idx = (size_t)bl * 1024 + ch;
  float um = (l > 0)    ? h[idx - 1024] : 0.f;
  float u0 = h[idx];
  float up = (l < 4095) ? h[idx + 1024] : 0.f;
  float v = um * k0 + u0 * k1 + up * k2;
  float o = v / (1.f + __expf(-v));  // silu
  if (ch < 512) { xb[(size_t)bl * 512 + c] = o; xbbf[(size_t)bl * 512 + c] = f2bf(o); }
  else          cat[idx] = f2bf(o);
}

// ---------------- split proj: dtr -> bf16, b/c -> tanh ----------------
__global__ __launch_bounds__(256) void prep_dtbc_kernel(
    const float* __restrict__ proj, unsigned short* __restrict__ dtr,
    float* __restrict__ bterm, float* __restrict__ cterm) {
  int i = blockIdx.x * 256 + threadIdx.x;  // 16384*128
  int row = i >> 7, col = i & 127;
  float v = proj[i];
  if (col < 64)      dtr[row * 64 + col] = f2bf(v);
  else if (col < 72) bterm[row * 8 + (col - 64)] = ftanh(v);
  else if (col < 80) cterm[row * 8 + (col - 72)] = ftanh(v);
}

// ---------------- chunked selective scan (128 chunks x 32 steps) ----------
// One thread owns one (b, c, chunk) with all 8 DSTATE lanes in registers.
// Lanes -> consecutive c: coalesced draw/xb; bterm/cterm wave-uniform broadcast.
// Summaries are chunk-major [chunk][bcs] for coalesced p1-store/p2/p3-load.
// delta = clip(softplus(draw + b_dt[c]), 1e-4, 1) computed inline.
__global__ __launch_bounds__(256) void scan_p1(
    const float* __restrict__ draw, const float* __restrict__ bterm,
    const float* __restrict__ xb, const float* __restrict__ A_log,
    const float* __restrict__ bdt,
    float* __restrict__ Aprod, float* __restrict__ Bpart) {
  int tid = threadIdx.x;
  int gid = blockIdx.x;
  int chunk = gid & 127, half = (gid >> 7) & 1, b = gid >> 8;
  int c = half * 256 + tid;
  float4 a0 = *(const float4*)&A_log[c * 8];
  float4 a1 = *(const float4*)&A_log[c * 8 + 4];
  float na[8] = {a0.x, a0.y, a0.z, a0.w, a1.x, a1.y, a1.z, a1.w};
#pragma unroll
  for (int s = 0; s < 8; ++s) na[s] = -(fsoftplus(na[s]) + 1e-4f);
  float bb = bdt[c];
  int l0 = chunk * 32;
  size_t base  = ((size_t)b * 4096 + l0) * 512 + c;
  size_t bbase = ((size_t)b * 4096 + l0) * 8;
  float S[8] = {}, Ap[8] = {1.f, 1.f, 1.f, 1.f, 1.f, 1.f, 1.f, 1.f};
  for (int i = 0; i < 32; ++i) {
    float dr = draw[base] + bb;
    float xv = xb[base];
    float delta = fminf(fmaxf(fsoftplus(dr), 1e-4f), 1.f);
    float4 bt0 = *(const float4*)&bterm[bbase];
    float4 bt1 = *(const float4*)&bterm[bbase + 4];
    float bt[8] = {bt0.x, bt0.y, bt0.z, bt0.w, bt1.x, bt1.y, bt1.z, bt1.w};
#pragma unroll
    for (int s = 0; s < 8; ++s) {
      float dec = fminf(fmaxf(__expf(delta * na[s]), 1e-4f), 1.f);
      float btx = bt[s] * xv;
      S[s] = dec * S[s] + (btx - dec * btx);
      Ap[s] *= dec;
    }
    base += 512; bbase += 8;
  }
  size_t o = (size_t)chunk * 16384 + ((size_t)(b * 512 + c)) * 8;
  *(float4*)&Aprod[o]     = make_float4(Ap[0], Ap[1], Ap[2], Ap[3]);
  *(float4*)&Aprod[o + 4] = make_float4(Ap[4], Ap[5], Ap[6], Ap[7]);
  *(float4*)&Bpart[o]     = make_float4(S[0], S[1], S[2], S[3]);
  *(float4*)&Bpart[o + 4] = make_float4(S[4], S[5], S[6], S[7]);
}

__global__ __launch_bounds__(256) void scan_p2(
    const float* __restrict__ Aprod, const float* __restrict__ Bpart,
    float* __restrict__ initst) {
  int t = blockIdx.x * 256 + threadIdx.x;  // 16384 threads: one (b,c,s)
  float st = 0.f;
  for (int ch = 0; ch < 128; ++ch) {
    size_t o = (size_t)ch * 16384 + t;
    initst[o] = st;
    st = Aprod[o] * st + Bpart[o];  // coalesced across threads
  }
}

__global__ __launch_bounds__(256) void scan_p3(
    const float* __restrict__ draw, const float* __restrict__ bterm,
    const float* __restrict__ cterm, const float* __restrict__ xb,
    const float* __restrict__ A_log, const float* __restrict__ bdt,
    const float* __restrict__ Dp,
    const float* __restrict__ initst, unsigned short* __restrict__ cat) {
  int tid = threadIdx.x;
  int gid = blockIdx.x;
  int chunk = gid & 127, half = (gid >> 7) & 1, b = gid >> 8;
  int c = half * 256 + tid;
  float4 a0 = *(const float4*)&A_log[c * 8];
  float4 a1 = *(const float4*)&A_log[c * 8 + 4];
  float na[8] = {a0.x, a0.y, a0.z, a0.w, a1.x, a1.y, a1.z, a1.w};
#pragma unroll
  for (int s = 0; s < 8; ++s) na[s] = -(fsoftplus(na[s]) + 1e-4f);
  float bb = bdt[c];
  float Dv = Dp[c];
  size_t o = (size_t)chunk * 16384 + ((size_t)(b * 512 + c)) * 8;
  float4 s0 = *(const float4*)&initst[o];
  float4 s1 = *(const float4*)&initst[o + 4];
  float S[8] = {s0.x, s0.y, s0.z, s0.w, s1.x, s1.y, s1.z, s1.w};
  int l0 = chunk * 32;
  size_t base  = ((size_t)b * 4096 + l0) * 512 + c;
  size_t bbase = ((size_t)b * 4096 + l0) * 8;
  size_t cbase = ((size_t)b * 4096 + l0) * 1024 + c;   // y -> cat[..., :512]
  for (int i = 0; i < 32; ++i) {
    float dr = draw[base] + bb;
    float xv = xb[base];
    float delta = fminf(fmaxf(fsoftplus(dr), 1e-4f), 1.f);
    float4 bt0 = *(const float4*)&bterm[bbase];
    float4 bt1 = *(const float4*)&bterm[bbase + 4];
    float4 ct0 = *(const float4*)&cterm[bbase];
    float4 ct1 = *(const float4*)&cterm[bbase + 4];
    float bt[8] = {bt0.x, bt0.y, bt0.z, bt0.w, bt1.x, bt1.y, bt1.z, bt1.w};
    float ct[8] = {ct0.x, ct0.y, ct0.z, ct0.w, ct1.x, ct1.y, ct1.z, ct1.w};
    float acc = Dv * xv;
#pragma unroll
    for (int s = 0; s < 8; ++s) {
      float dec = fminf(fmaxf(__expf(delta * na[s]), 1e-4f), 1.f);
      float btx = bt[s] * xv;
      S[s] = dec * S[s] + (btx - dec * btx);
      acc += S[s] * ct[s];
    }
    cat[cbase] = f2bf(acc);
    base += 512; bbase += 8; cbase += 1024;
  }
}

// ---------------- launch ----------------
extern "C" void kernel_launch(void* const* d_in, const int* in_sizes, int n_in,
                              void* d_out, int out_size, void* d_ws, size_t ws_size,
                              hipStream_t stream) {
  (void)in_sizes; (void)n_in; (void)out_size; (void)ws_size;
  const float* x       = (const float*)d_in[0];
  const float* W_in    = (const float*)d_in[1];
  const float* Kx      = (const float*)d_in[2];
  const float* Kz      = (const float*)d_in[3];
  const float* W_xproj = (const float*)d_in[4];
  const float* W_dt    = (const float*)d_in[5];
  const float* b_dt    = (const float*)d_in[6];
  const float* A_log   = (const float*)d_in[7];
  const float* Dp      = (const float*)d_in[8];
  const float* W_out   = (const float*)d_in[9];
  float* out = (float*)d_out;

  // workspace layout (133.4 MB) with dead-buffer overlays
  char* w = (char*)d_ws;
  unsigned short* xbf  = (unsigned short*)(w);               // 33.5MB x bf16; reused as cat
  float* xb    = (float*)(w + 33554432);                     // 33.5MB fp32 xb (scan)
  float* draw  = (float*)(w + 67108864);                     // 33.5MB delta_raw; head = proj
  float* bterm = (float*)(w + 100663296);                    // 0.5MB
  float* cterm = (float*)(w + 101187584);                    // 0.5MB
  float* Aprod = (float*)(w + 101711872);                    // 8MB [chunk][bcs]
  float* Bpart = (float*)(w + 110100480);                    // 8MB
  float* initst = (float*)(w + 118489088);                   // 8MB
  unsigned short* winbf  = (unsigned short*)(w + 126877696); // 2MB
  unsigned short* woutbf = (unsigned short*)(w + 128974848); // 2MB
  unsigned short* dtr    = (unsigned short*)(w + 131072000); // 2MB (16384x64 bf16)
  unsigned short* wxp_bf = (unsigned short*)(w + 133169152); // 128KB
  unsigned short* wd_bf  = (unsigned short*)(w + 133300224); // 64KB  (end 133365760)
  unsigned short* xbbf = (unsigned short*)Aprod;             // 16.8MB overlay; dead before scan_p1
  float* proj = draw;                                        // 16384x128 head; dead before delta-gemm
  float* h = out;  // d_out doubles as h scratch (fully rewritten by final GEMM)

  cvt_bf16_kernel<<<16384, 256, 0, stream>>>(x, xbf, 4194304);
  cvt_bf16_kernel<<<1024, 256, 0, stream>>>(W_in, winbf, 262144);
  cvt_bf16_kernel<<<1024, 256, 0, stream>>>(W_out, woutbf, 262144);
  cvt_bf16_kernel<<<32, 256, 0, stream>>>(W_dt, wd_bf, 8192);
  cvt_wxp_kernel<<<256, 256, 0, stream>>>(W_xproj, wxp_bf);

  gemm_bt_bf16<<<dim3(128, 8), 256, 0, stream>>>(xbf, winbf, h, 16384, 1024, 1024);

  conv_silu_kernel<<<65536, 256, 0, stream>>>(h, Kx, Kz, xb, xbbf, xbf /*cat*/);

  gemm_bt_bf16<<<dim3(128, 1), 256, 0, stream>>>(xbbf, wxp_bf, proj, 16384, 128, 512);
  prep_dtbc_kernel<<<8192, 256, 0, stream>>>(proj, dtr, bterm, cterm);
  gemm_bt_bf16<<<dim3(128, 4), 256, 0, stream>>>(dtr, wd_bf, draw, 16384, 512, 64);

  scan_p1<<<1024, 256, 0, stream>>>(draw, bterm, xb, A_log, b_dt, Aprod, Bpart);
  scan_p2<<<64, 256, 0, stream>>>(Aprod, Bpart, initst);
  scan_p3<<<1024, 256, 0, stream>>>(draw, bterm, cterm, xb, A_log, b_dt, Dp, initst, xbf /*cat*/);

  gemm_bt_bf16<<<dim3(128, 8), 256, 0, stream>>>(xbf, woutbf, out, 16384, 1024, 1024);
}